// Round 11
// baseline (317.757 us; speedup 1.0000x reference)
//
#include <hip/hip_runtime.h>
#include <hip/hip_bf16.h>

// DifferentiableXGB: logits = epilogue(x @ W1^T + b1)
//   split[b,n] = sum_d x[b,d]*W1[n,d] + b1[n]          (n = t*4+k, N=400)
//   S[b,t] = sum_k split[b,t,k]
//   logits[b,j] = sum_t fw[t]*S[b,t]*sum_k sigmoid(split[b,t,k])*fc_w[j,k] + fc_b[j]
//
// V19 = B DIRECT-FROM-L2 (no B staging at all) + tiny-LDS co-residency.
// R17 model (fit over V8..V18): t = F*chunks + s*BK*chunks with F~5.5kcy
// fixed per barrier-chunk, s~110cy/kcol serialized. So (1) keep chunks=16
// (BK=64; the 32-chunk variants all lost), (2) delete the whole B leg:
// W1 bf16 = 0.9MB is L2-resident and ALREADY bf16 in ws -> feed MFMA B
// operands straight from L2 into named ping-pong regs (zero VALU, no DMA,
// no LDS round-trip, no drain). LDS shrinks to A-dbuf 16KB + P 2KB = 18KB
// -> with 4-wave blocks (~245 unified regs) TWO blocks/CU co-reside on
// both LDS and regs; two independent barrier domains hide each other's
// fixed cost. No manual vmcnt needed: the only barrier dep is A ds_writes
// (lgkmcnt(0)); all global loads stay in flight across the raw s_barrier
// (compiler emits exact counted vmcnt at each named-reg consumption).
//   - 256 thr = 4 waves (wave = nf 0..3), BM=64, BK=64, NCHUNK=16,
//     NT=7 (NPAD=448), MT=4 -> acc 112 AGPR. Grid 512 (m-split only).
//   - A: reg-staged depth-2 (sets X/Y, 32 VGPR), 2 subs/thread,
//     V8-verified swizzle phys_sub=(sub+row)&7 on 64-short rows.
//   - B: 7 ptrs/wave-lane; per half-chunk h: 7 dwordx4 -> set h^1 while
//     computing set h (ping-pong 2x28 VGPR); ~half-chunk cover >> L2 lat.
//   - pad cols >=400: B=0 (ws pad), tw=bias=0 in epilogue -> exact zeros.
//   - launch_bounds(256,2): 2 waves/SIMD budget 256 unified regs.

typedef __bf16 bf16x8 __attribute__((ext_vector_type(8)));
typedef float f32x4 __attribute__((ext_vector_type(4)));

#define B_ROWS 32768
#define D_DIM  1024
#define N_COLS 400
#define NPAD   448
#define BM     64
#define BK     64
#define NCHUNK 16          // 1024 / 64
#define THREADS 256        // 4 waves: nf = wave
#define NTPW 7             // n-tiles (16 wide) per wave (4*7 = 28 = 448)
#define MT   4             // m-tiles (16 tall) per wave (64 rows)

__device__ __forceinline__ unsigned short f2bf(float f) {
    unsigned int u = __float_as_uint(f);
    u += 0x7FFFu + ((u >> 16) & 1u);   // RTNE
    return (unsigned short)(u >> 16);
}
__device__ __forceinline__ unsigned int pk2(float a, float b) {
    return (unsigned int)f2bf(a) | ((unsigned int)f2bf(b) << 16);
}
__device__ __forceinline__ uint4 cvt8u(float4 a, float4 b) {
    uint4 u;
    u.x = pk2(a.x, a.y); u.y = pk2(a.z, a.w);
    u.z = pk2(b.x, b.y); u.w = pk2(b.z, b.w);
    return u;
}
__device__ __forceinline__ bf16x8 cvt8(float4 a, float4 b) {
    return __builtin_bit_cast(bf16x8, cvt8u(a, b));
}

// W1 fp32 [400][1024] -> bf16 [448][1024] zero-padded (0.9 MB in ws)
__global__ void cvt_pad_bf16_kernel(const float* __restrict__ in,
                                    unsigned short* __restrict__ out) {
    size_t i = ((size_t)blockIdx.x * 256 + threadIdx.x) * 8;   // < 448*1024
    if (i < (size_t)N_COLS * D_DIM) {
        float4 v0 = *reinterpret_cast<const float4*>(in + i);
        float4 v1 = *reinterpret_cast<const float4*>(in + i + 4);
        *reinterpret_cast<uint4*>(out + i) = cvt8u(v0, v1);
    } else {
        uint4 z; z.x = z.y = z.z = z.w = 0u;
        *reinterpret_cast<uint4*>(out + i) = z;
    }
}

// ---- macro machinery: every hot value is an individually named register ----
#define FOR_N_(OP, m) OP(m,0) OP(m,1) OP(m,2) OP(m,3) OP(m,4) OP(m,5) OP(m,6)
#define FOR_MN(OP) FOR_N_(OP,0) FOR_N_(OP,1) FOR_N_(OP,2) FOR_N_(OP,3)

#define DECL_ACC(m,n) f32x4 acc##m##n = {};
#define MFMA_MN(m,n) acc##m##n = __builtin_amdgcn_mfma_f32_16x16x32_bf16( \
        afr##m, bfr##n, acc##m##n, 0, 0, 0);

// MODE 0: A staged via LDS, B direct-from-L2 (ws). MODE 2: both fp32 direct.
template <int MODE>
__global__ __launch_bounds__(THREADS, 2) void xgb_v19(
    const float* __restrict__ x,
    const void*  __restrict__ b_any,
    const float* __restrict__ b1,
    const float* __restrict__ fw,
    const float* __restrict__ fcw,      // [2,4]
    const float* __restrict__ fcb,      // [2]
    float* __restrict__ out)            // [B,2]
{
    // A rows of 64 shorts (128 B), sub = 8 shorts (16 B), 8 subs/row;
    // swizzle: phys_sub = (sub + row) & 7   (V8-verified)
    __shared__ __align__(16) unsigned short Abuf[2][BM * BK];       // 16 KB
    __shared__ float Pbuf[BM * 4 * 2];                              // 2 KB

    const int tid  = threadIdx.x;
    const int wave = tid >> 6;          // 0..3
    const int lane = tid & 63;
    const int quad = lane >> 4;
    const int l15  = lane & 15;
    const int nf   = wave;              // n quarter: 7 tiles
    const int row0 = blockIdx.x * BM;

    FOR_MN(DECL_ACC)                    // acc00..acc36, 28 x f32x4

    if (MODE == 0) {
        const unsigned short* w1b = (const unsigned short*)b_any;

        // ---- A staging: 64 rows x 8 subs = 512 subs = 2/thread
        // (slot tid -> row tid>>3, slot tid+256 -> row +32, same sub).
        const int r0a = tid >> 3, c0a = tid & 7;
        const float* asrc0 = x + (size_t)(row0 + r0a) * D_DIM + c0a * 8;
        const float* asrc1 = asrc0 + (size_t)32 * D_DIM;
        const int adst0 = r0a * 64 + ((c0a + r0a) & 7) * 8;   // swizzled
        // (c0a + r0a + 32) & 7 == (c0a + r0a) & 7 -> adst1 = adst0 + 2048
        float4 aRX0, aRX1, aRX2, aRX3;      // set X (A of even chunks)
        float4 aRY0, aRY1, aRY2, aRY3;      // set Y (A of odd chunks)

#define LOADA(S, kc) do { \
        aR##S##0 = *reinterpret_cast<const float4*>(asrc0 + (kc));     \
        aR##S##1 = *reinterpret_cast<const float4*>(asrc0 + (kc) + 4); \
        aR##S##2 = *reinterpret_cast<const float4*>(asrc1 + (kc));     \
        aR##S##3 = *reinterpret_cast<const float4*>(asrc1 + (kc) + 4); } while (0)
#define WRITEA(S, Ab) do { \
        *reinterpret_cast<uint4*>((Ab) + adst0)        = cvt8u(aR##S##0, aR##S##1); \
        *reinterpret_cast<uint4*>((Ab) + adst0 + 2048) = cvt8u(aR##S##2, aR##S##3); \
        } while (0)

        // ---- B pointers: fragment (n,h) at row (nf*7+n)*16 + l15,
        // cols quad*8 + h*32 .. +7  ->  one dwordx4 per (n,h).
#define BPDECL(n) const unsigned short* pb##n = \
        w1b + (size_t)((nf * NTPW + (n)) * 16 + l15) * D_DIM + quad * 8;
        BPDECL(0) BPDECL(1) BPDECL(2) BPDECL(3) BPDECL(4) BPDECL(5) BPDECL(6)

        // ping-pong B sets (7 x uint4 each)
        uint4 bA0, bA1, bA2, bA3, bA4, bA5, bA6;   // set A
        uint4 bB0, bB1, bB2, bB3, bB4, bB5, bB6;   // set B

#define BLOAD(S, kc, h) do { \
        b##S##0 = *reinterpret_cast<const uint4*>(pb0 + (kc) + (h) * 32); \
        b##S##1 = *reinterpret_cast<const uint4*>(pb1 + (kc) + (h) * 32); \
        b##S##2 = *reinterpret_cast<const uint4*>(pb2 + (kc) + (h) * 32); \
        b##S##3 = *reinterpret_cast<const uint4*>(pb3 + (kc) + (h) * 32); \
        b##S##4 = *reinterpret_cast<const uint4*>(pb4 + (kc) + (h) * 32); \
        b##S##5 = *reinterpret_cast<const uint4*>(pb5 + (kc) + (h) * 32); \
        b##S##6 = *reinterpret_cast<const uint4*>(pb6 + (kc) + (h) * 32); } while (0)

#define LOAD_AFR(m, h) { const int row_ = (m) * 16 + l15; \
        const int p_ = (quad + (h) * 4 + row_) & 7; \
        afr##m = *reinterpret_cast<const bf16x8*>(Ab_ + row_ * 64 + p_ * 8); }

#define COMPUTE_H(S, h) do { \
        bf16x8 afr0, afr1, afr2, afr3; \
        LOAD_AFR(0, h) LOAD_AFR(1, h) LOAD_AFR(2, h) LOAD_AFR(3, h) \
        bf16x8 bfr0 = __builtin_bit_cast(bf16x8, b##S##0); \
        bf16x8 bfr1 = __builtin_bit_cast(bf16x8, b##S##1); \
        bf16x8 bfr2 = __builtin_bit_cast(bf16x8, b##S##2); \
        bf16x8 bfr3 = __builtin_bit_cast(bf16x8, b##S##3); \
        bf16x8 bfr4 = __builtin_bit_cast(bf16x8, b##S##4); \
        bf16x8 bfr5 = __builtin_bit_cast(bf16x8, b##S##5); \
        bf16x8 bfr6 = __builtin_bit_cast(bf16x8, b##S##6); \
        FOR_MN(MFMA_MN) \
        } while (0)

        // PH = c&1. A(c+1) lives in set[ (c+1)&1 ] = PH^1; A(c+2) loads
        // into set[PH]. Chunk body; one raw barrier at the end.
#define CHUNK_BODY(PH, WS, LS, cc) do { \
        const int c_ = (cc) + (PH); \
        const int kc_ = c_ * BK; \
        const unsigned short* Ab_ = Abuf[PH]; \
        BLOAD(B, kc_, 1);                         /* B(c,h1) -> set B */ \
        COMPUTE_H(A, 0);                          /* h0 with set A   */ \
        if (c_ + 1 < NCHUNK) BLOAD(A, kc_ + BK, 0); /* B(c+1,h0)     */ \
        if (c_ + 2 < NCHUNK) LOADA(LS, kc_ + 2 * BK); \
        COMPUTE_H(B, 1);                          /* h1 with set B   */ \
        if (c_ + 1 < NCHUNK) WRITEA(WS, Abuf[PH ^ 1]); \
        asm volatile("s_waitcnt lgkmcnt(0)" ::: "memory"); \
        __builtin_amdgcn_sched_barrier(0); \
        __builtin_amdgcn_s_barrier(); \
        } while (0)

        // ---- prologue ----
        LOADA(X, 0);                    // A(0)
        BLOAD(A, 0, 0);                 // B(0,h0) -> set A
        WRITEA(X, Abuf[0]);             // compiler waits A(0) (one-time)
        LOADA(Y, BK);                   // A(1) stays in flight
        asm volatile("s_waitcnt lgkmcnt(0)" ::: "memory");
        __builtin_amdgcn_sched_barrier(0);
        __builtin_amdgcn_s_barrier();

        #pragma unroll 1
        for (int cc = 0; cc < NCHUNK; cc += 2) {
            CHUNK_BODY(0, Y, X, cc);    // even chunk: write A(c+1) from Y,
            CHUNK_BODY(1, X, Y, cc);    //   load A(c+2) into X; odd: swap
        }
    } else {
        // fallback: both fp32 direct (no ws), clamped pad cols, plain loop
        const float* af = x + (size_t)(row0 + l15) * D_DIM + quad * 8;
#define PBF(n) const float* pbf##n; { \
        int r_ = (nf * NTPW + (n)) * 16 + l15; if (r_ > N_COLS - 1) r_ = 0; \
        pbf##n = (const float*)b_any + (size_t)r_ * D_DIM + quad * 8; }
        PBF(0) PBF(1) PBF(2) PBF(3) PBF(4) PBF(5) PBF(6)
        for (int step = 0; step < 32; ++step) {
            const int off = step * 32;
            bf16x8 afr0, afr1, afr2, afr3;
            bf16x8 bfr0, bfr1, bfr2, bfr3, bfr4, bfr5, bfr6;
#define LAF2(m) afr##m = cvt8( \
            *reinterpret_cast<const float4*>(af + (size_t)(m) * 16 * D_DIM + off), \
            *reinterpret_cast<const float4*>(af + (size_t)(m) * 16 * D_DIM + off + 4));
#define LBF2(n) bfr##n = cvt8( \
            *reinterpret_cast<const float4*>(pbf##n + off), \
            *reinterpret_cast<const float4*>(pbf##n + off + 4));
            LAF2(0) LAF2(1) LAF2(2) LAF2(3)
            LBF2(0) LBF2(1) LBF2(2) LBF2(3) LBF2(4) LBF2(5) LBF2(6)
            FOR_MN(MFMA_MN)
        }
    }

    // ---- epilogue ----
    // C/D layout: col = l15 (within tile), row = quad*4 + reg   [m89/m91]
    const float fcw0 = fcw[l15 & 3];        // fc_w[0][k], k = col&3
    const float fcw1 = fcw[4 + (l15 & 3)];  // fc_w[1][k]

    // pad cols (>=400): bias=0, tw=0 -> exact zero contribution
#define PRE_N(n) \
    const int  col##n  = (nf * NTPW + (n)) * 16 + l15; \
    const bool ok##n   = (col##n < N_COLS); \
    const float bias##n = ok##n ? b1[ok##n ? col##n : 0] : 0.0f; \
    const float tw##n   = ok##n ? fw[ok##n ? (col##n >> 2) : 0] : 0.0f;
    PRE_N(0) PRE_N(1) PRE_N(2) PRE_N(3) PRE_N(4) PRE_N(5) PRE_N(6)

    // per (m,r): q = sum over n of fw[t]*sigmoid(split)*S ; then 16-lane sum.
    // k-sum S: lanes ^1,^2 (l15 bits 0-1 are k within tree).
#define EPI_TERM(m,r,n) { \
        const float split_ = acc##m##n[r] + bias##n; \
        float s_ = split_; \
        s_ += __shfl_xor(s_, 1); \
        s_ += __shfl_xor(s_, 2); \
        const float leaf_ = 1.0f / (1.0f + __expf(-split_)); \
        const float val_ = tw##n * leaf_ * s_; \
        q0 += val_ * fcw0; q1 += val_ * fcw1; }

#define EPI_ONE(m,r) { \
        float q0 = 0.f, q1 = 0.f; \
        EPI_TERM(m,r,0) EPI_TERM(m,r,1) EPI_TERM(m,r,2) EPI_TERM(m,r,3) \
        EPI_TERM(m,r,4) EPI_TERM(m,r,5) EPI_TERM(m,r,6) \
        q0 += __shfl_xor(q0, 1); q0 += __shfl_xor(q0, 2); \
        q0 += __shfl_xor(q0, 4); q0 += __shfl_xor(q0, 8); \
        q1 += __shfl_xor(q1, 1); q1 += __shfl_xor(q1, 2); \
        q1 += __shfl_xor(q1, 4); q1 += __shfl_xor(q1, 8); \
        const int row_ = (m) * 16 + quad * 4 + (r);           /* 0..63 */ \
        if (l15 == 0) Pbuf[(row_ * 4 + nf) * 2 + 0] = q0; \
        if (l15 == 1) Pbuf[(row_ * 4 + nf) * 2 + 1] = q1; }

#define EPI_M(m) EPI_ONE(m,0) EPI_ONE(m,1) EPI_ONE(m,2) EPI_ONE(m,3)
    EPI_M(0) EPI_M(1) EPI_M(2) EPI_M(3)

    __syncthreads();

    if (tid < 2 * BM) {
        const int r = tid >> 1, j = tid & 1;
        float s = fcb[j];
        #pragma unroll
        for (int w = 0; w < 4; ++w)
            s += Pbuf[(r * 4 + w) * 2 + j];
        out[(size_t)(row0 + r) * 2 + j] = s;
    }
}

extern "C" void kernel_launch(void* const* d_in, const int* in_sizes, int n_in,
                              void* d_out, int out_size, void* d_ws, size_t ws_size,
                              hipStream_t stream) {
    const float* x   = (const float*)d_in[0];
    const float* W1  = (const float*)d_in[1];
    const float* b1  = (const float*)d_in[2];
    const float* fw  = (const float*)d_in[3];
    const float* fcw = (const float*)d_in[4];
    const float* fcb = (const float*)d_in[5];
    float* out = (float*)d_out;

    const size_t pad_elems = (size_t)NPAD * D_DIM;    // 458,752
    if (ws_size >= pad_elems * sizeof(unsigned short)) {
        unsigned short* w1b = (unsigned short*)d_ws;
        cvt_pad_bf16_kernel<<<(int)(pad_elems / 2048), 256, 0, stream>>>(W1, w1b);
        xgb_v19<0><<<B_ROWS / BM, THREADS, 0, stream>>>(
            x, (const void*)w1b, b1, fw, fcw, fcb, out);
    } else {
        xgb_v19<2><<<B_ROWS / BM, THREADS, 0, stream>>>(
            x, (const void*)W1, b1, fw, fcw, fcb, out);
    }
}

// Round 12
// 231.429 us; speedup vs baseline: 1.3730x; 1.3730x over previous
//
#include <hip/hip_runtime.h>
#include <hip/hip_bf16.h>

// DifferentiableXGB: logits = epilogue(x @ W1^T + b1)
//   split[b,n] = sum_d x[b,d]*W1[n,d] + b1[n]          (n = t*4+k, N=400)
//   S[b,t] = sum_k split[b,t,k]
//   logits[b,j] = sum_t fw[t]*S[b,t]*sum_k sigmoid(split[b,t,k])*fc_w[j,k] + fc_b[j]
//
// V20 = V14 (best, 83us) + m201-style PHASE GATING (T3 minimum form) + T5.
// R18 post-mortem: V19 (B direct-from-L2) spilled (WRITE 222MB, 1.7KB/thr
// scratch: 56 B-VGPR + 32 A + 112 acc blew 256) -> reverted. V14's gap:
// one monolithic 56-MFMA blob per chunk behind one barrier; MfmaUtil 13.5%.
// V20 splits each chunk into TWO barrier-gated phases (h0/h1), each:
//   {11 ds_read frags + staging share} -> s_barrier -> lgkmcnt(0) ->
//   setprio(1) 28 MFMA setprio(0)
// All waves enter MFMA clusters TOGETHER (matrix pipe packed); stage ops
// issue in the gaps; T5 has a role-split to arbitrate (m218b/m224 gate).
// Dataflow/ledger = V14 exactly:
//   - BM=128, BK=64, NCHUNK=16, 512 thr = 8 waves (2mh x 4nf), NT=7
//     (NPAD=448), MT=4, acc 112. Grid 256. LDS 148KB.
//   - A: 2 subs/thread, depth-2 ping-pong sets X/Y; B: 56 DMA stages,
//     7/wave (phase0: t=0..3, phase1: t=4..6).
//   - ledger: top of chunk c outstanding = 7 DMA(c) + 4 A(c+1) -> vmcnt(4)
//     (c<=14), vmcnt(0) at c=15. WRITEA's implicit wait retires A(c+1)
//     mid-chunk; phase-1 lgkm(0) drains the ds_write before its barrier.
// Hazard audit (3 barriers/chunk: B1 top, B2/B3 phase gates):
//   - RAW buffer c: B1 after per-wave vmcnt retire of own DMA(c) + all
//     WRITEA(c) drained via prior phase-1 lgkm(0) before arrival.
//   - WAR buffer 1-cur: all reads of it finished before each wave ARRIVES
//     at B1 (reads drained at phase lgkm(0)); STAGEB(c+1)/WRITEA(c+1)
//     issue only after B1.
//   - B2/B3 are pure scheduling gates, no correctness role.

typedef __bf16 bf16x8 __attribute__((ext_vector_type(8)));
typedef float f32x4 __attribute__((ext_vector_type(4)));

#define B_ROWS 32768
#define D_DIM  1024
#define N_COLS 400
#define NPAD   448
#define BM     128
#define BK     64
#define NCHUNK 16          // 1024 / 64
#define THREADS 512        // 8 waves: mh = wave>>2, nf = wave&3
#define NTPW 7             // n-tiles (16 wide) per wave (4*7 = 28 = 448)
#define MT   4             // m-tiles (16 tall) per wave (64 rows per mh)

__device__ __forceinline__ unsigned short f2bf(float f) {
    unsigned int u = __float_as_uint(f);
    u += 0x7FFFu + ((u >> 16) & 1u);   // RTNE
    return (unsigned short)(u >> 16);
}
__device__ __forceinline__ unsigned int pk2(float a, float b) {
    return (unsigned int)f2bf(a) | ((unsigned int)f2bf(b) << 16);
}
__device__ __forceinline__ uint4 cvt8u(float4 a, float4 b) {
    uint4 u;
    u.x = pk2(a.x, a.y); u.y = pk2(a.z, a.w);
    u.z = pk2(b.x, b.y); u.w = pk2(b.z, b.w);
    return u;
}
__device__ __forceinline__ bf16x8 cvt8(float4 a, float4 b) {
    return __builtin_bit_cast(bf16x8, cvt8u(a, b));
}

// W1 fp32 [400][1024] -> bf16 [448][1024] zero-padded (0.9 MB in ws)
__global__ void cvt_pad_bf16_kernel(const float* __restrict__ in,
                                    unsigned short* __restrict__ out) {
    size_t i = ((size_t)blockIdx.x * 256 + threadIdx.x) * 8;   // < 448*1024
    if (i < (size_t)N_COLS * D_DIM) {
        float4 v0 = *reinterpret_cast<const float4*>(in + i);
        float4 v1 = *reinterpret_cast<const float4*>(in + i + 4);
        *reinterpret_cast<uint4*>(out + i) = cvt8u(v0, v1);
    } else {
        uint4 z; z.x = z.y = z.z = z.w = 0u;
        *reinterpret_cast<uint4*>(out + i) = z;
    }
}

// async 16B/lane global->LDS; lds dest = wave-uniform base + lane*16 (HW)
__device__ __forceinline__ void gl_lds16(const unsigned short* g,
                                         unsigned short* l) {
    __builtin_amdgcn_global_load_lds(
        (const __attribute__((address_space(1))) unsigned int*)g,
        (__attribute__((address_space(3))) unsigned int*)l,
        16, 0, 0);
}

// ---- macro machinery: every hot value is an individually named register ----
#define FOR_N_(OP, m) OP(m,0) OP(m,1) OP(m,2) OP(m,3) OP(m,4) OP(m,5) OP(m,6)
#define FOR_MN(OP) FOR_N_(OP,0) FOR_N_(OP,1) FOR_N_(OP,2) FOR_N_(OP,3)

#define DECL_ACC(m,n) f32x4 acc##m##n = {};
#define MFMA_MN(m,n) acc##m##n = __builtin_amdgcn_mfma_f32_16x16x32_bf16( \
        afr##m, bfr##n, acc##m##n, 0, 0, 0);

// MODE 0: phase-gated pipeline (ws). MODE 2: both fp32 direct (insurance).
template <int MODE>
__global__ __launch_bounds__(THREADS, 2) void xgb_v20(
    const float* __restrict__ x,
    const void*  __restrict__ b_any,
    const float* __restrict__ b1,
    const float* __restrict__ fw,
    const float* __restrict__ fcw,      // [2,4]
    const float* __restrict__ fcb,      // [2]
    float* __restrict__ out)            // [B,2]
{
    // rows of 64 shorts (128 B), sub = 8 shorts (16 B), 8 subs/row;
    // swizzle: phys_sub = (sub + row) & 7   (V8-verified)
    __shared__ __align__(16) unsigned short Abuf[2][BM * BK];       // 32 KB
    __shared__ __align__(16) unsigned short Bbuf[2][NPAD * BK];     // 112 KB
    __shared__ float Pbuf[BM * 4 * 2];                              // 4 KB

    const int tid  = threadIdx.x;
    const int wave = tid >> 6;          // 0..7
    const int lane = tid & 63;
    const int quad = lane >> 4;
    const int l15  = lane & 15;
    const int mh   = wave >> 2;         // 0..1  (m half: 64 rows)
    const int nf   = wave & 3;          // 0..3  (n quarter: 7 tiles)
    const int row0 = blockIdx.x * BM;

    FOR_MN(DECL_ACC)                    // acc00..acc36, 28 x f32x4

    if (MODE == 0) {
        const unsigned short* w1b = (const unsigned short*)b_any;

        // ---- B staging: 56 DMA stages (8 rows = 1 KB each), 7 per wave.
        // stage s covers rows 8s..8s+7. lane i -> row 8s+(i>>3), phys slot
        // i&7; fetch the logical sub for that slot: ((i&7) - row) & 7.
#define BDECL(t) const unsigned short* bsrc##t; int bdst##t; \
        { const int s_ = wave + 8 * (t); const int rr_ = lane >> 3; \
          const int cc_ = ((lane & 7) - rr_) & 7; \
          bsrc##t = w1b + (size_t)(s_ * 8 + rr_) * D_DIM + cc_ * 8; \
          bdst##t = s_ * 512; }                    // shorts
        BDECL(0) BDECL(1) BDECL(2) BDECL(3) BDECL(4) BDECL(5) BDECL(6)

#define STAGEB_P0(kc, Bb) do { \
        gl_lds16(bsrc0 + (kc), (Bb) + bdst0); \
        gl_lds16(bsrc1 + (kc), (Bb) + bdst1); \
        gl_lds16(bsrc2 + (kc), (Bb) + bdst2); \
        gl_lds16(bsrc3 + (kc), (Bb) + bdst3); } while (0)
#define STAGEB_P1(kc, Bb) do { \
        gl_lds16(bsrc4 + (kc), (Bb) + bdst4); \
        gl_lds16(bsrc5 + (kc), (Bb) + bdst5); \
        gl_lds16(bsrc6 + (kc), (Bb) + bdst6); } while (0)

        // ---- A staging: 128 rows x 8 subs = 1024 subs; 512 thr x 2 slots
        // UNIFORM: slot0 = tid, slot1 = tid + 512 (= +64 rows, same column
        // -> same swizzle phase, dest +64 rows).
        const int r0a = tid >> 3, c0a = tid & 7;
        const float* asrc0 = x + (size_t)(row0 + r0a) * D_DIM + c0a * 8;
        const float* asrc1 = asrc0 + (size_t)64 * D_DIM;
        const int adst0 = r0a * 64 + ((c0a + r0a) & 7) * 8;   // swizzled
        // (c0a + r0a + 64) & 7 == (c0a + r0a) & 7  ->  adst1 = adst0 + 4096
        // depth-2 ping-pong fp32 sets X/Y; A(c) lives in set c&1
        float4 aX0lo, aX0hi, aX1lo, aX1hi;
        float4 aY0lo, aY0hi, aY1lo, aY1hi;

#define LOADA_X(kc) do { \
        aX0lo = *reinterpret_cast<const float4*>(asrc0 + (kc));     \
        aX0hi = *reinterpret_cast<const float4*>(asrc0 + (kc) + 4); \
        aX1lo = *reinterpret_cast<const float4*>(asrc1 + (kc));     \
        aX1hi = *reinterpret_cast<const float4*>(asrc1 + (kc) + 4); } while (0)
#define LOADA_Y(kc) do { \
        aY0lo = *reinterpret_cast<const float4*>(asrc0 + (kc));     \
        aY0hi = *reinterpret_cast<const float4*>(asrc0 + (kc) + 4); \
        aY1lo = *reinterpret_cast<const float4*>(asrc1 + (kc));     \
        aY1hi = *reinterpret_cast<const float4*>(asrc1 + (kc) + 4); } while (0)
#define WRITEA_X(Ab) do { \
        *reinterpret_cast<uint4*>((Ab) + adst0)        = cvt8u(aX0lo, aX0hi); \
        *reinterpret_cast<uint4*>((Ab) + adst0 + 4096) = cvt8u(aX1lo, aX1hi); \
        } while (0)
#define WRITEA_Y(Ab) do { \
        *reinterpret_cast<uint4*>((Ab) + adst0)        = cvt8u(aY0lo, aY0hi); \
        *reinterpret_cast<uint4*>((Ab) + adst0 + 4096) = cvt8u(aY1lo, aY1hi); \
        } while (0)

#define LOAD_AFR(m, H) { const int row_ = mh * 64 + (m) * 16 + l15; \
        const int p_ = (quad + (H) * 4 + row_) & 7; \
        afr##m = *reinterpret_cast<const bf16x8*>(Ab_ + row_ * 64 + p_ * 8); }
#define LOAD_BFR(n, H) { const int row_ = (nf * NTPW + (n)) * 16 + l15; \
        const int p_ = (quad + (H) * 4 + row_) & 7; \
        bfr##n = *reinterpret_cast<const bf16x8*>(Bb_ + row_ * 64 + p_ * 8); }

        // ---- prologue (issue order pinned for the ledger):
        // A(0) loads -> WRITEA (implicit drain) -> 7 DMA(0) -> A(1) loads.
        LOADA_X(0);
        WRITEA_X(Abuf[0]);
        __builtin_amdgcn_sched_barrier(0);
        STAGEB_P0(0, Bbuf[0]);
        STAGEB_P1(0, Bbuf[0]);
        __builtin_amdgcn_sched_barrier(0);
        LOADA_Y(BK);                    // A(1) stays in flight
        asm volatile("s_waitcnt lgkmcnt(0)" ::: "memory");  // A(0) ds_write
        __builtin_amdgcn_sched_barrier(0);

        #pragma unroll 1
        for (int c = 0; c < NCHUNK; ++c) {
            const int cur = c & 1;
            const unsigned short* Ab_ = Abuf[cur];
            const unsigned short* Bb_ = Bbuf[cur];
            const int kc1 = (c + 1) * BK;
            // ---- B1: chunk boundary. Retire own DMA(c); A(c+1) flies on.
            if (c <= NCHUNK - 2) {
                asm volatile("s_waitcnt vmcnt(4)" ::: "memory");
            } else {
                asm volatile("s_waitcnt vmcnt(0)" ::: "memory");
            }
            __builtin_amdgcn_sched_barrier(0);
            __builtin_amdgcn_s_barrier();
            __builtin_amdgcn_sched_barrier(0);
            // ================= phase 0 (k-half h=0) =================
            {
                bf16x8 afr0, afr1, afr2, afr3;
                bf16x8 bfr0, bfr1, bfr2, bfr3, bfr4, bfr5, bfr6;
                LOAD_AFR(0, 0) LOAD_AFR(1, 0) LOAD_AFR(2, 0) LOAD_AFR(3, 0)
                LOAD_BFR(0, 0) LOAD_BFR(1, 0) LOAD_BFR(2, 0) LOAD_BFR(3, 0)
                LOAD_BFR(4, 0) LOAD_BFR(5, 0) LOAD_BFR(6, 0)
                if (c + 1 < NCHUNK) STAGEB_P0(kc1, Bbuf[1 - cur]);
                __builtin_amdgcn_sched_barrier(0);
                __builtin_amdgcn_s_barrier();           // B2 (phase gate)
                asm volatile("s_waitcnt lgkmcnt(0)" ::: "memory");
                __builtin_amdgcn_sched_barrier(0);
                __builtin_amdgcn_s_setprio(1);
                FOR_MN(MFMA_MN)
                __builtin_amdgcn_s_setprio(0);
            }
            // ================= phase 1 (k-half h=1) =================
            {
                bf16x8 afr0, afr1, afr2, afr3;
                bf16x8 bfr0, bfr1, bfr2, bfr3, bfr4, bfr5, bfr6;
                LOAD_AFR(0, 1) LOAD_AFR(1, 1) LOAD_AFR(2, 1) LOAD_AFR(3, 1)
                LOAD_BFR(0, 1) LOAD_BFR(1, 1) LOAD_BFR(2, 1) LOAD_BFR(3, 1)
                LOAD_BFR(4, 1) LOAD_BFR(5, 1) LOAD_BFR(6, 1)
                if (c + 1 < NCHUNK) {
                    STAGEB_P1(kc1, Bbuf[1 - cur]);
                    // A(c+1) lives in set (c+1)&1 = cur^1; implicit vmcnt
                    // wait retires those 4 loads (issued a full chunk ago).
                    if (cur == 0) WRITEA_Y(Abuf[1]);
                    else          WRITEA_X(Abuf[0]);
                }
                if (c + 2 < NCHUNK) {                  // A(c+2) -> set cur
                    if (cur == 0) LOADA_X((c + 2) * BK);
                    else          LOADA_Y((c + 2) * BK);
                }
                __builtin_amdgcn_sched_barrier(0);
                __builtin_amdgcn_s_barrier();           // B3 (phase gate)
                asm volatile("s_waitcnt lgkmcnt(0)" ::: "memory");
                __builtin_amdgcn_sched_barrier(0);
                __builtin_amdgcn_s_setprio(1);
                FOR_MN(MFMA_MN)
                __builtin_amdgcn_s_setprio(0);
            }
        }
    } else {
        // fallback: both fp32 direct (no ws), clamped pad cols, plain loop
        const float* af = x + (size_t)(row0 + mh * 64 + l15) * D_DIM + quad * 8;
#define PBF(n) const float* pbf##n; { \
        int r_ = (nf * NTPW + (n)) * 16 + l15; if (r_ > N_COLS - 1) r_ = 0; \
        pbf##n = (const float*)b_any + (size_t)r_ * D_DIM + quad * 8; }
        PBF(0) PBF(1) PBF(2) PBF(3) PBF(4) PBF(5) PBF(6)
        for (int step = 0; step < 32; ++step) {
            const int off = step * 32;
            bf16x8 afr0, afr1, afr2, afr3;
            bf16x8 bfr0, bfr1, bfr2, bfr3, bfr4, bfr5, bfr6;
#define LAF2(m) afr##m = cvt8( \
            *reinterpret_cast<const float4*>(af + (size_t)(m) * 16 * D_DIM + off), \
            *reinterpret_cast<const float4*>(af + (size_t)(m) * 16 * D_DIM + off + 4));
#define LBF2(n) bfr##n = cvt8( \
            *reinterpret_cast<const float4*>(pbf##n + off), \
            *reinterpret_cast<const float4*>(pbf##n + off + 4));
            LAF2(0) LAF2(1) LAF2(2) LAF2(3)
            LBF2(0) LBF2(1) LBF2(2) LBF2(3) LBF2(4) LBF2(5) LBF2(6)
            FOR_MN(MFMA_MN)
        }
    }

    // ---- epilogue ----
    // C/D layout: col = l15 (within tile), row = quad*4 + reg   [m89/m91]
    const float fcw0 = fcw[l15 & 3];        // fc_w[0][k], k = col&3
    const float fcw1 = fcw[4 + (l15 & 3)];  // fc_w[1][k]

    // pad cols (>=400): bias=0, tw=0 -> exact zero contribution
#define PRE_N(n) \
    const int  col##n  = (nf * NTPW + (n)) * 16 + l15; \
    const bool ok##n   = (col##n < N_COLS); \
    const float bias##n = ok##n ? b1[ok##n ? col##n : 0] : 0.0f; \
    const float tw##n   = ok##n ? fw[ok##n ? (col##n >> 2) : 0] : 0.0f;
    PRE_N(0) PRE_N(1) PRE_N(2) PRE_N(3) PRE_N(4) PRE_N(5) PRE_N(6)

    // per (m,r): q = sum over n of fw[t]*sigmoid(split)*S ; then 16-lane sum.
    // k-sum S: lanes ^1,^2 (l15 bits 0-1 are k within tree).
#define EPI_TERM(m,r,n) { \
        const float split_ = acc##m##n[r] + bias##n; \
        float s_ = split_; \
        s_ += __shfl_xor(s_, 1); \
        s_ += __shfl_xor(s_, 2); \
        const float leaf_ = 1.0f / (1.0f + __expf(-split_)); \
        const float val_ = tw##n * leaf_ * s_; \
        q0 += val_ * fcw0; q1 += val_ * fcw1; }

#define EPI_ONE(m,r) { \
        float q0 = 0.f, q1 = 0.f; \
        EPI_TERM(m,r,0) EPI_TERM(m,r,1) EPI_TERM(m,r,2) EPI_TERM(m,r,3) \
        EPI_TERM(m,r,4) EPI_TERM(m,r,5) EPI_TERM(m,r,6) \
        q0 += __shfl_xor(q0, 1); q0 += __shfl_xor(q0, 2); \
        q0 += __shfl_xor(q0, 4); q0 += __shfl_xor(q0, 8); \
        q1 += __shfl_xor(q1, 1); q1 += __shfl_xor(q1, 2); \
        q1 += __shfl_xor(q1, 4); q1 += __shfl_xor(q1, 8); \
        const int row_ = mh * 64 + (m) * 16 + quad * 4 + (r);   /* 0..127 */ \
        if (l15 == 0) Pbuf[(row_ * 4 + nf) * 2 + 0] = q0; \
        if (l15 == 1) Pbuf[(row_ * 4 + nf) * 2 + 1] = q1; }

#define EPI_M(m) EPI_ONE(m,0) EPI_ONE(m,1) EPI_ONE(m,2) EPI_ONE(m,3)
    EPI_M(0) EPI_M(1) EPI_M(2) EPI_M(3)

    __syncthreads();

    if (tid < 2 * BM) {
        const int r = tid >> 1, j = tid & 1;
        float s = fcb[j];
        #pragma unroll
        for (int w = 0; w < 4; ++w)
            s += Pbuf[(r * 4 + w) * 2 + j];
        out[(size_t)(row0 + r) * 2 + j] = s;
    }
}

extern "C" void kernel_launch(void* const* d_in, const int* in_sizes, int n_in,
                              void* d_out, int out_size, void* d_ws, size_t ws_size,
                              hipStream_t stream) {
    const float* x   = (const float*)d_in[0];
    const float* W1  = (const float*)d_in[1];
    const float* b1  = (const float*)d_in[2];
    const float* fw  = (const float*)d_in[3];
    const float* fcw = (const float*)d_in[4];
    const float* fcb = (const float*)d_in[5];
    float* out = (float*)d_out;

    const size_t pad_elems = (size_t)NPAD * D_DIM;    // 458,752
    if (ws_size >= pad_elems * sizeof(unsigned short)) {
        unsigned short* w1b = (unsigned short*)d_ws;
        cvt_pad_bf16_kernel<<<(int)(pad_elems / 2048), 256, 0, stream>>>(W1, w1b);
        xgb_v20<0><<<B_ROWS / BM, THREADS, 0, stream>>>(
            x, (const void*)w1b, b1, fw, fcw, fcb, out);
    } else {
        xgb_v20<2><<<B_ROWS / BM, THREADS, 0, stream>>>(
            x, (const void*)W1, b1, fw, fcw, fcb, out);
    }
}